// Round 7
// baseline (665.382 us; speedup 1.0000x reference)
//
#include <hip/hip_runtime.h>

// GCN 2-layer + mean-pool + readout, transform-first:
//   z[u]  = (norm_out[u]*x[u]) @ W1                     (f32, dense)
//   h1[n] = relu( norm_in[n] * Sum_{e:dst=n} z[src_e] + b1 )
//   out   = ((1/N) Sum_n cw[n]*h1[n]) @ W2 + b2 @ Wr^T + br
//   cw[n] = norm_out[n]*c_raw[n],  c_raw[u] = Sum_{e:src=u} norm_in[dst_e]
// R6 lesson: local float arrays + lambdas -> scratch/collapsed pipeline
// (VGPR=40, 13MB scratch writes, ~9 lines in flight/CU). R7: all prefetch
// values are NAMED scalars via macros; launch_bounds(256,4) = 128-reg budget.

constexpr int NN = 50000;
constexpr int NE = 800000;
constexpr int ZROW = NN;

// ws dword offsets
constexpr int OFF_DEG_OUT = 0;        // int[50000]  zeroed
constexpr int OFF_DEG_IN  = 50000;    // int[50000]  zeroed
constexpr int OFF_CRAW    = 100000;   // f32[50000]  zeroed
constexpr int OFF_PART    = 150000;   // f32[32*96]  zeroed
constexpr int OFF_TICKET  = 153072;   // int zeroed
constexpr int OFF_ALLOC   = 153073;   // int zeroed
constexpr size_t ZERO_DW  = 153088;
constexpr int OFF_ROW_PTR = 153088;   // int[50000]
constexpr int OFF_CURSOR  = 203088;   // int[50000]
constexpr int OFF_SLOTS   = 253088;   // int[1000000]
constexpr int SLOTS_CAP   = 1000000;
constexpr int OFF_Z       = 1253088;  // f32[(50001)*96]

__global__ void k_deg(const int4* __restrict__ src4, const int4* __restrict__ dst4,
                      int* __restrict__ deg_out, int* __restrict__ deg_in) {
  int i = blockIdx.x * blockDim.x + threadIdx.x;
  if (i < NE / 4) {
    int4 s = src4[i], d = dst4[i];
    atomicAdd(&deg_out[s.x], 1); atomicAdd(&deg_out[s.y], 1);
    atomicAdd(&deg_out[s.z], 1); atomicAdd(&deg_out[s.w], 1);
    atomicAdd(&deg_in[d.x], 1);  atomicAdd(&deg_in[d.y], 1);
    atomicAdd(&deg_in[d.z], 1);  atomicAdd(&deg_in[d.w], 1);
  }
}

// z = (norm_out*x)@W1, f32 out.
__global__ __launch_bounds__(256)
void k_gemm(const float* __restrict__ x, const int* __restrict__ deg_out,
            const float* __restrict__ W1, float* __restrict__ z) {
  int tid = threadIdx.x;
  __shared__ float W1s[96 * 96];
  for (int i = tid; i < 96 * 96 / 4; i += 256)
    ((float4*)W1s)[i] = ((const float4*)W1)[i];
  __syncthreads();

  int wave = tid >> 6, ll = tid & 31, hl = (tid >> 5) & 1;
  for (int task = blockIdx.x * 4 + wave; task < NN / 2; task += 1024 * 4) {
    int n = task * 2 + hl;
    float no = rsqrtf((float)max(deg_out[n], 1));
    const float* xr = x + (size_t)n * 96;
    float v0 = xr[ll] * no, v1 = xr[ll + 32] * no, v2 = xr[ll + 64] * no;
    float h0 = 0.f, h1 = 0.f, h2 = 0.f;
#pragma unroll
    for (int kb = 0; kb < 3; ++kb) {
      float vsrc = kb == 0 ? v0 : (kb == 1 ? v1 : v2);
#pragma unroll
      for (int kk = 0; kk < 32; ++kk) {
        int k = kb * 32 + kk;
        float vk = __shfl(vsrc, kk, 32);
        h0 = fmaf(vk, W1s[k * 96 + ll], h0);
        h1 = fmaf(vk, W1s[k * 96 + ll + 32], h1);
        h2 = fmaf(vk, W1s[k * 96 + ll + 64], h2);
      }
    }
    float* zr = z + (size_t)n * 96;
    zr[ll] = h0; zr[ll + 32] = h1; zr[ll + 64] = h2;
  }
}

// Wave-level segment alloc (exact degree); also zeroes z's ZROW row.
__global__ void k_alloc(const int* __restrict__ deg_in, int* __restrict__ alloc,
                        int* __restrict__ row_ptr, int* __restrict__ cursor,
                        float* __restrict__ z) {
  int n = blockIdx.x * blockDim.x + threadIdx.x;
  if (blockIdx.x == 0 && threadIdx.x < 96) z[(size_t)ZROW * 96 + threadIdx.x] = 0.f;
  int l = threadIdx.x & 63;
  int pd = 0;
  if (n < NN) pd = deg_in[n];
  int incl = pd;
#pragma unroll
  for (int o = 1; o < 64; o <<= 1) {
    int u = __shfl_up(incl, o, 64);
    if (l >= o) incl += u;
  }
  int base = 0;
  if (l == 63) base = atomicAdd(alloc, incl);
  base = __shfl(base, 63, 64);
  if (n < NN) { int p = base + incl - pd; row_ptr[n] = p; cursor[n] = p; }
}

// Counting scatter by dst (4 edges/thread) + c_raw accumulation.
__global__ void k_scatter(const int4* __restrict__ src4, const int4* __restrict__ dst4,
                          const int* __restrict__ deg_in, int* __restrict__ cursor,
                          int* __restrict__ slots, float* __restrict__ c_raw) {
  int i = blockIdx.x * blockDim.x + threadIdx.x;
  if (i < NE / 4) {
    int4 s = src4[i], d = dst4[i];
    int p0 = atomicAdd(&cursor[d.x], 1);
    int p1 = atomicAdd(&cursor[d.y], 1);
    int p2 = atomicAdd(&cursor[d.z], 1);
    int p3 = atomicAdd(&cursor[d.w], 1);
    slots[p0] = s.x; slots[p1] = s.y; slots[p2] = s.z; slots[p3] = s.w;
    atomicAdd(&c_raw[s.x], rsqrtf((float)max(deg_in[d.x], 1)));
    atomicAdd(&c_raw[s.y], rsqrtf((float)max(deg_in[d.y], 1)));
    atomicAdd(&c_raw[s.z], rsqrtf((float)max(deg_in[d.z], 1)));
    atomicAdd(&c_raw[s.w], rsqrtf((float)max(deg_in[d.w], 1)));
  }
}

// Fetch 4 edge-rows (12 dwords) into NAMED registers. T is wave-uniform.
#define FETCH4(T, BK, RP, E, X0,X1,X2,X3,X4,X5,X6,X7,X8,X9,X10,X11)          \
  {                                                                          \
    int _i0 = (T), _i1 = (T)+1, _i2 = (T)+2, _i3 = (T)+3;                    \
    int _s0, _s1, _s2, _s3;                                                  \
    if (_i0 < 32) {                                                          \
      int _b = half << 5;                                                    \
      _s0 = __shfl((BK), _b+_i0, 64); _s1 = __shfl((BK), _b+_i1, 64);        \
      _s2 = __shfl((BK), _b+_i2, 64); _s3 = __shfl((BK), _b+_i3, 64);        \
    } else {                                                                 \
      _s0 = slots[min((RP)+_i0, SLOTS_CAP-1)];                               \
      _s1 = slots[min((RP)+_i1, SLOTS_CAP-1)];                               \
      _s2 = slots[min((RP)+_i2, SLOTS_CAP-1)];                               \
      _s3 = slots[min((RP)+_i3, SLOTS_CAP-1)];                               \
    }                                                                        \
    _s0 = _i0 < (E) ? _s0 : ZROW;  _s1 = _i1 < (E) ? _s1 : ZROW;             \
    _s2 = _i2 < (E) ? _s2 : ZROW;  _s3 = _i3 < (E) ? _s3 : ZROW;             \
    const float* _r0 = z + (size_t)_s0 * 96 + ll;                            \
    const float* _r1 = z + (size_t)_s1 * 96 + ll;                            \
    const float* _r2 = z + (size_t)_s2 * 96 + ll;                            \
    const float* _r3 = z + (size_t)_s3 * 96 + ll;                            \
    X0 = _r0[0]; X1  = _r0[32]; X2  = _r0[64];                               \
    X3 = _r1[0]; X4  = _r1[32]; X5  = _r1[64];                               \
    X6 = _r2[0]; X7  = _r2[32]; X8  = _r2[64];                               \
    X9 = _r3[0]; X10 = _r3[32]; X11 = _r3[64];                               \
  }

#define ACC3(A0,A1,A2, X0,X1,X2,X3,X4,X5,X6,X7,X8,X9,X10,X11)                \
  A0 += ((X0+X3)+(X6+X9)); A1 += ((X1+X4)+(X7+X10)); A2 += ((X2+X5)+(X8+X11));

// One node per HALF-wave, 4 edges/round, 2-deep rotated prefetch, named regs.
#define PHASE(BK, RP, E, EM, A0, A1, A2)                                     \
  {                                                                          \
    A0 = 0.f; A1 = 0.f; A2 = 0.f;                                            \
    if ((EM) > 0) {                                                          \
      float p0,p1,p2,p3,p4,p5,p6,p7,p8,p9,p10,p11;                           \
      float q0,q1,q2,q3,q4,q5,q6,q7,q8,q9,q10,q11;                           \
      FETCH4(0, BK, RP, E, p0,p1,p2,p3,p4,p5,p6,p7,p8,p9,p10,p11);           \
      int _t = 4;                                                            \
      for (;;) {                                                             \
        if (_t < (EM)) {                                                     \
          FETCH4(_t, BK, RP, E, q0,q1,q2,q3,q4,q5,q6,q7,q8,q9,q10,q11);      \
          ACC3(A0,A1,A2, p0,p1,p2,p3,p4,p5,p6,p7,p8,p9,p10,p11);             \
          _t += 4;                                                           \
        } else {                                                             \
          ACC3(A0,A1,A2, p0,p1,p2,p3,p4,p5,p6,p7,p8,p9,p10,p11);             \
          break;                                                             \
        }                                                                    \
        if (_t < (EM)) {                                                     \
          FETCH4(_t, BK, RP, E, p0,p1,p2,p3,p4,p5,p6,p7,p8,p9,p10,p11);      \
          ACC3(A0,A1,A2, q0,q1,q2,q3,q4,q5,q6,q7,q8,q9,q10,q11);             \
          _t += 4;                                                           \
        } else {                                                             \
          ACC3(A0,A1,A2, q0,q1,q2,q3,q4,q5,q6,q7,q8,q9,q10,q11);             \
          break;                                                             \
        }                                                                    \
      }                                                                      \
    }                                                                        \
  }

__global__ __launch_bounds__(256, 4)
void k_gather(const float* __restrict__ z,
              const int* __restrict__ deg_in, const int* __restrict__ deg_out,
              const float* __restrict__ c_raw,
              const int* __restrict__ row_ptr, const int* __restrict__ slots,
              const float* __restrict__ b1,
              const float* __restrict__ W2, const float* __restrict__ b2,
              const float* __restrict__ Wr, const float* __restrict__ br,
              int* __restrict__ ticket,
              float* __restrict__ part, float* __restrict__ out) {
  __shared__ float red[96];
  __shared__ float sg[96], hg[96];
  __shared__ int lastflag;
  const int tid = threadIdx.x, l = tid & 63;
  const int ll = l & 31, half = l >> 5;
  if (tid < 96) red[tid] = 0.f;
  __syncthreads();

  float bb0 = b1[ll], bb1 = b1[ll + 32], bb2 = b1[ll + 64];
  float as0 = 0.f, as1 = 0.f, as2 = 0.f;

  const int NTILES = NN / 4;        // 12500
  const int nwaves = gridDim.x * 4;
  for (int tile = blockIdx.x * 4 + (tid >> 6); tile < NTILES; tile += nwaves) {
    int n0 = tile * 4;

    int mrp = 0, mdi = 0, mdg = 0; float mcr = 0.f;
    if (l < 4)       mrp = row_ptr[n0 + l];
    else if (l < 8)  mdi = deg_in[n0 + (l - 4)];
    else if (l < 12) mdg = deg_out[n0 + (l - 8)];
    else if (l < 16) mcr = c_raw[n0 + (l - 12)];
    int rp0 = __shfl(mrp, 0, 64), rp1 = __shfl(mrp, 1, 64),
        rp2 = __shfl(mrp, 2, 64), rp3 = __shfl(mrp, 3, 64);
    int di0 = __shfl(mdi, 4, 64), di1 = __shfl(mdi, 5, 64),
        di2 = __shfl(mdi, 6, 64), di3 = __shfl(mdi, 7, 64);
    int dg0 = __shfl(mdg, 8, 64),  dg1 = __shfl(mdg, 9, 64),
        dg2 = __shfl(mdg, 10, 64), dg3 = __shfl(mdg, 11, 64);
    float cr0 = __shfl(mcr, 12, 64), cr1 = __shfl(mcr, 13, 64),
          cr2 = __shfl(mcr, 14, 64), cr3 = __shfl(mcr, 15, 64);

    // half A: nodes n0, n0+1 ; half B: nodes n0+2, n0+3
    int rpF = half ? rp2 : rp0,  rpS = half ? rp3 : rp1;
    int eF  = half ? di2 : di0,  eS  = half ? di3 : di1;
    int emF = max(di0, di2),     emS = max(di1, di3);
    int bkF = slots[min(rpF + ll, SLOTS_CAP - 1)];
    int bkS = slots[min(rpS + ll, SLOTS_CAP - 1)];

    float a0, a1, a2;
    PHASE(bkF, rpF, eF, emF, a0, a1, a2);
    {
      float ni = rsqrtf((float)max(eF, 1));
      int   dg = half ? dg2 : dg0;
      float cr = half ? cr2 : cr0;
      float cw = rsqrtf((float)max(dg, 1)) * cr;
      as0 = fmaf(cw, fmaxf(fmaf(ni, a0, bb0), 0.f), as0);
      as1 = fmaf(cw, fmaxf(fmaf(ni, a1, bb1), 0.f), as1);
      as2 = fmaf(cw, fmaxf(fmaf(ni, a2, bb2), 0.f), as2);
    }
    PHASE(bkS, rpS, eS, emS, a0, a1, a2);
    {
      float ni = rsqrtf((float)max(eS, 1));
      int   dg = half ? dg3 : dg1;
      float cr = half ? cr3 : cr1;
      float cw = rsqrtf((float)max(dg, 1)) * cr;
      as0 = fmaf(cw, fmaxf(fmaf(ni, a0, bb0), 0.f), as0);
      as1 = fmaf(cw, fmaxf(fmaf(ni, a1, bb1), 0.f), as1);
      as2 = fmaf(cw, fmaxf(fmaf(ni, a2, bb2), 0.f), as2);
    }
  }

  // fold halves (same columns), then one half writes to LDS
  as0 += __shfl_xor(as0, 32, 64);
  as1 += __shfl_xor(as1, 32, 64);
  as2 += __shfl_xor(as2, 32, 64);
  if (half == 0) {
    atomicAdd(&red[ll], as0);
    atomicAdd(&red[ll + 32], as1);
    atomicAdd(&red[ll + 64], as2);
  }
  __syncthreads();
  // bucketed global partials: 32 buckets of 96
  if (tid < 96) atomicAdd(&part[(blockIdx.x & 31) * 96 + tid], red[tid]);
  __threadfence();
  __syncthreads();
  if (tid == 0) {
    int tk = atomicAdd(ticket, 1);
    lastflag = (tk == (int)gridDim.x - 1);
  }
  __syncthreads();
  if (lastflag) {
    if (tid < 96) {
      float s = 0.f;
      for (int b = 0; b < 32; ++b)
        s += atomicAdd(&part[b * 96 + tid], 0.0f);   // coherent read
      sg[tid] = s;
    }
    __syncthreads();
    if (tid < 96) {
      float acc = b2[tid];
      const float invN = 1.0f / (float)NN;
      for (int k = 0; k < 96; ++k)
        acc = fmaf(sg[k] * invN, W2[k * 96 + tid], acc);
      hg[tid] = acc;
    }
    __syncthreads();
    if (tid < 8) {
      float acc = br[tid];
      for (int k = 0; k < 96; ++k)
        acc = fmaf(hg[k], Wr[tid * 96 + k], acc);
      out[tid] = acc;
    }
  }
}

extern "C" void kernel_launch(void* const* d_in, const int* in_sizes, int n_in,
                              void* d_out, int out_size, void* d_ws, size_t ws_size,
                              hipStream_t stream) {
  const float* feats = (const float*)d_in[0];
  const int*   src   = (const int*)d_in[1];
  const int*   dst   = (const int*)d_in[2];
  const float* W1    = (const float*)d_in[3];
  const float* b1    = (const float*)d_in[4];
  const float* W2    = (const float*)d_in[5];
  const float* b2    = (const float*)d_in[6];
  const float* Wr    = (const float*)d_in[7];
  const float* br    = (const float*)d_in[8];
  float* out = (float*)d_out;

  int*   wsi = (int*)d_ws;
  float* wsf = (float*)d_ws;
  int*   deg_out = wsi + OFF_DEG_OUT;
  int*   deg_in  = wsi + OFF_DEG_IN;
  float* c_raw   = wsf + OFF_CRAW;
  float* part    = wsf + OFF_PART;
  int*   ticket  = wsi + OFF_TICKET;
  int*   alloc   = wsi + OFF_ALLOC;
  int*   row_ptr = wsi + OFF_ROW_PTR;
  int*   cursor  = wsi + OFF_CURSOR;
  int*   slots   = wsi + OFF_SLOTS;
  float* z       = wsf + OFF_Z;

  hipMemsetAsync(d_ws, 0, ZERO_DW * 4, stream);

  k_deg<<<(NE / 4 + 255) / 256, 256, 0, stream>>>((const int4*)src, (const int4*)dst,
                                                  deg_out, deg_in);
  k_gemm<<<1024, 256, 0, stream>>>(feats, deg_out, W1, z);
  k_alloc<<<(NN + 255) / 256, 256, 0, stream>>>(deg_in, alloc, row_ptr, cursor, z);
  k_scatter<<<(NE / 4 + 255) / 256, 256, 0, stream>>>((const int4*)src, (const int4*)dst,
                                                      deg_in, cursor, slots, c_raw);
  k_gather<<<3125, 256, 0, stream>>>(z, deg_in, deg_out, c_raw, row_ptr, slots,
                                     b1, W2, b2, Wr, br, ticket, part, out);
}